// Round 21
// baseline (252.754 us; speedup 1.0000x reference)
//
#include <hip/hip_runtime.h>

typedef _Float16 hp2 __attribute__((ext_vector_type(2)));

#define NB    1024
#define TT    256
#define EE    100
#define VOCAB 5000
#define GG1   256   // 4*H1
#define GG2   128   // 4*H2

__device__ __forceinline__ float fast_sigmoid(float x) {
  return __builtin_amdgcn_rcpf(1.0f + __expf(-x));
}
__device__ __forceinline__ float fast_tanh(float x) {
  return 1.0f - 2.0f * __builtin_amdgcn_rcpf(1.0f + __expf(2.0f * x));
}

// Counted-wait barrier: drain LDS ops only; global zx prefetch stays in flight.
__device__ __forceinline__ void step_sync() {
  asm volatile("s_waitcnt lgkmcnt(0)" ::: "memory");
  __builtin_amdgcn_s_barrier();
  __builtin_amdgcn_sched_barrier(0);
}

// Pin 16 consecutive 32-bit values into architectural VGPRs.
#define PIN16(A, B) asm volatile("" : "+v"((A)[B+0]),"+v"((A)[B+1]),"+v"((A)[B+2]),"+v"((A)[B+3]),\
  "+v"((A)[B+4]),"+v"((A)[B+5]),"+v"((A)[B+6]),"+v"((A)[B+7]),"+v"((A)[B+8]),"+v"((A)[B+9]),\
  "+v"((A)[B+10]),"+v"((A)[B+11]),"+v"((A)[B+12]),"+v"((A)[B+13]),"+v"((A)[B+14]),"+v"((A)[B+15]))

// ---- K1: emb_zi[v][u*4+g] = b1[g*64+u] + sum_k emb[v][k]*W1[k][g*64+u] ----
__global__ __launch_bounds__(256) void emb_gemm(
    const float* __restrict__ emb, const float* __restrict__ W1,
    const float* __restrict__ b1, float* __restrict__ emb_zi)
{
  __shared__ float sE[8][EE];
  const int j  = threadIdx.x;           // column g*64+u
  const int v0 = blockIdx.x * 8;
  for (int idx = j; idx < 8 * EE; idx += 256) {
    int r = idx / EE, k = idx % EE;
    sE[r][k] = emb[(size_t)(v0 + r) * EE + k];
  }
  __syncthreads();
  float acc[8];
  const float bb = b1[j];
  #pragma unroll
  for (int r = 0; r < 8; ++r) acc[r] = bb;
  for (int k = 0; k < EE; ++k) {
    float w = W1[k * GG1 + j];
    #pragma unroll
    for (int r = 0; r < 8; ++r) acc[r] = fmaf(sE[r][k], w, acc[r]);
  }
  const int slot = (j & 63) * 4 + (j >> 6);   // u*4 + g
  #pragma unroll
  for (int r = 0; r < 8; ++r) emb_zi[(size_t)(v0 + r) * GG1 + slot] = acc[r];
}

// ---- K2: one block = one row, FOUR waves, unit-split, 1 barrier/step ----
// Identical to round-19 (correctness-proven) + weight pins (anti-AGPR-demotion)
// + s_setprio around dot clusters. 1024 blocks x 4 waves = 4 waves/SIMD.
__global__ __launch_bounds__(256) __attribute__((amdgpu_waves_per_eu(4, 4)))
void lstm_quad(
    const int* __restrict__ tokens, const float* __restrict__ emb_zi,
    const float* __restrict__ U1,
    const float* __restrict__ W2, const float* __restrict__ U2, const float* __restrict__ b2,
    const float* __restrict__ Wd, const float* __restrict__ bd,
    float* __restrict__ out)
{
  __shared__ __align__(16) _Float16 sHB[2][96];  // 0..63 h1, 64..95 h2
  __shared__ int sTok[TT];

  const int tid = threadIdx.x;
  const int l   = tid & 63;
  const int wv  = tid >> 6;           // wave role 0..3
  const int row = blockIdx.x;

  // ---- stage tokens + zero h buffers ----
  if (tid < 128) ((int2*)sTok)[tid] = ((const int2*)(tokens + (size_t)row * TT))[tid];
  if (tid < 96) { sHB[0][tid] = (_Float16)0.0f; sHB[1][tid] = (_Float16)0.0f; }

  if (wv < 2) {
    // ================= L1 wave: units [32*wv, 32*wv+32) =================
    const int ul = l & 31;
    const int s  = l >> 5;            // k-half: k in [32s, 32s+32)
    const int u  = 32 * wv + ul;
    hp2 wA[64];   // wA[4p+g] = {U1[k0][g*64+u], U1[k0+1][g*64+u]}, k0 = 32s+2p
    #pragma unroll
    for (int p = 0; p < 16; ++p) {
      int k0 = 32 * s + 2 * p;
      #pragma unroll
      for (int g = 0; g < 4; ++g) {
        hp2 w;
        w[0] = (_Float16)U1[(k0 + 0) * GG1 + g * 64 + u];
        w[1] = (_Float16)U1[(k0 + 1) * GG1 + g * 64 + u];
        wA[4 * p + g] = w;
      }
    }
    PIN16(wA, 0); PIN16(wA, 16); PIN16(wA, 32); PIN16(wA, 48);
    __syncthreads();                  // tokens + zeroed buffers visible

    float c1 = 0.f, h1r = 0.f;
    // ---- prologue: h1(0) from zx(0); s-pair redundant ----
    {
      int tok0 = sTok[0];
      float4 zx0 = *(const float4*)&emb_zi[(size_t)tok0 * GG1 + 4 * u];
      if (tok0 != 0) {
        float iv = fast_sigmoid(zx0.x);
        float gv = fast_tanh(zx0.z);
        float ov = fast_sigmoid(zx0.w);
        c1 = iv * gv; h1r = ov * fast_tanh(c1);
      }
      if (s == 0) sHB[0][u] = (_Float16)h1r;
    }
    int   tok_a = sTok[1];            // token(t+1) for the A-step
    float4 zxa = *(const float4*)&emb_zi[(size_t)tok_a * GG1 + 4 * u];
    step_sync();

    for (int t = 0; t < TT; ++t) {
      if (t + 1 < TT) {               // ---- compute h1(t+1) from h1(t) ----
        // prefetch zx(t+2): rides across the barrier (lgkm-only sync)
        int tok_n = 0;
        float4 zxn = zxa;
        if (t + 2 < TT) {
          tok_n = sTok[t + 2];
          zxn = *(const float4*)&emb_zi[(size_t)tok_n * GG1 + 4 * u];
        }
        float a0 = 0.f, a1 = 0.f, a2 = 0.f, a3 = 0.f;
        const int4* rb = (const int4*)&sHB[t & 1][32 * s];  // this lane's k-half
        __builtin_amdgcn_s_setprio(1);
        #pragma unroll
        for (int q = 0; q < 4; ++q) {           // 4 x b128 = 32 halves = 16 pairs
          int4 hq = rb[q];
          #pragma unroll
          for (int pp = 0; pp < 4; ++pp) {
            const int p = 4 * q + pp;
            hp2 hv = ((const hp2*)&hq)[pp];
            a0 = __builtin_amdgcn_fdot2(hv, wA[4 * p + 0], a0, false);
            a1 = __builtin_amdgcn_fdot2(hv, wA[4 * p + 1], a1, false);
            a2 = __builtin_amdgcn_fdot2(hv, wA[4 * p + 2], a2, false);
            a3 = __builtin_amdgcn_fdot2(hv, wA[4 * p + 3], a3, false);
          }
        }
        __builtin_amdgcn_s_setprio(0);
        a0 += __shfl_xor(a0, 32);     // combine k-halves (in-wave)
        a1 += __shfl_xor(a1, 32);
        a2 += __shfl_xor(a2, 32);
        a3 += __shfl_xor(a3, 32);
        {
          const bool ma = (tok_a != 0);
          float iv = fast_sigmoid(a0 + zxa.x);
          float fv = fast_sigmoid(a1 + zxa.y);
          float gv = fast_tanh(a2 + zxa.z);
          float ov = fast_sigmoid(a3 + zxa.w);
          if (ma) { c1 = fv * c1 + iv * gv; h1r = ov * fast_tanh(c1); }
        }
        if (s == 0) sHB[(t & 1) ^ 1][u] = (_Float16)h1r;
        tok_a = tok_n; zxa = zxn;
      }
      step_sync();
    }
  } else {
    // ================= L2 wave: units [16*(wv-2), 16*(wv-2)+16) =================
    const int u2 = 16 * (wv - 2) + (l & 15);
    const int ss = l >> 4;            // k-quarter: k in [24ss, 24ss+24)
    hp2 wB[48];   // wB[4p+g] = combined [W2;U2] k-pair, k0 = 24ss+2p, col g*32+u2
    #pragma unroll
    for (int p = 0; p < 12; ++p) {
      int k0 = 24 * ss + 2 * p;       // even: never straddles the 64 boundary
      const float* r0 = (k0     < 64) ? &W2[(size_t)k0 * GG2]       : &U2[(size_t)(k0 - 64) * GG2];
      const float* r1 = (k0 + 1 < 64) ? &W2[(size_t)(k0 + 1) * GG2] : &U2[(size_t)(k0 + 1 - 64) * GG2];
      #pragma unroll
      for (int g = 0; g < 4; ++g) {
        hp2 w;
        w[0] = (_Float16)r0[g * 32 + u2];
        w[1] = (_Float16)r1[g * 32 + u2];
        wB[4 * p + g] = w;
      }
    }
    PIN16(wB, 0); PIN16(wB, 16); PIN16(wB, 32);
    const float bi2 = b2[u2], bf2 = b2[32 + u2], bg2 = b2[64 + u2], bo2 = b2[96 + u2];
    __syncthreads();                  // tokens + zeroed buffers visible

    float c2 = 0.f, h2r = 0.f;
    step_sync();                      // pairs with L1 prologue sync

    for (int t = 0; t < TT; ++t) {
      // ---- h2(t) from [h1(t) | h2(t-1)] at parity t&1 ----
      const int tok_b = sTok[t];
      float b0 = 0.f, b1v = 0.f, b2v = 0.f, b3 = 0.f;
      const int4* hbp = (const int4*)(&sHB[t & 1][24 * ss]);  // 4 addrs/wave
      __builtin_amdgcn_s_setprio(1);
      #pragma unroll
      for (int q = 0; q < 3; ++q) {             // 3 x b128 = 24 halves = 12 pairs
        int4 hq = hbp[q];
        #pragma unroll
        for (int pp = 0; pp < 4; ++pp) {
          const int p = 4 * q + pp;
          hp2 hv = ((const hp2*)&hq)[pp];
          b0  = __builtin_amdgcn_fdot2(hv, wB[4 * p + 0], b0,  false);
          b1v = __builtin_amdgcn_fdot2(hv, wB[4 * p + 1], b1v, false);
          b2v = __builtin_amdgcn_fdot2(hv, wB[4 * p + 2], b2v, false);
          b3  = __builtin_amdgcn_fdot2(hv, wB[4 * p + 3], b3,  false);
        }
      }
      __builtin_amdgcn_s_setprio(0);
      b0  += __shfl_xor(b0, 16);  b0  += __shfl_xor(b0, 32);
      b1v += __shfl_xor(b1v, 16); b1v += __shfl_xor(b1v, 32);
      b2v += __shfl_xor(b2v, 16); b2v += __shfl_xor(b2v, 32);
      b3  += __shfl_xor(b3, 16);  b3  += __shfl_xor(b3, 32);
      {
        const bool mb = (tok_b != 0);
        float i2 = fast_sigmoid(b0 + bi2);
        float f2 = fast_sigmoid(b1v + bf2);
        float g2 = fast_tanh(b2v + bg2);
        float o2 = fast_sigmoid(b3 + bo2);
        if (mb) { c2 = f2 * c2 + i2 * g2; h2r = o2 * fast_tanh(c2); }
      }
      if (ss == 0) sHB[(t & 1) ^ 1][64 + u2] = (_Float16)h2r;
      step_sync();
    }
  }
  __syncthreads();

  // ---- epilogue: h2(TT-1) in parity ((TT-1)&1)^1 = 0 ----
  if (tid < 4) {
    float a = bd[tid];
    #pragma unroll
    for (int k = 0; k < 32; ++k)
      a = fmaf((float)sHB[0][64 + k], Wd[k * 4 + tid], a);
    out[(size_t)row * 4 + tid] = fast_sigmoid(a);
  }
}

extern "C" void kernel_launch(void* const* d_in, const int* in_sizes, int n_in,
                              void* d_out, int out_size, void* d_ws, size_t ws_size,
                              hipStream_t stream) {
  const int*   tokens = (const int*)d_in[0];
  const float* emb    = (const float*)d_in[1];
  const float* W1     = (const float*)d_in[2];
  const float* U1     = (const float*)d_in[3];
  const float* b1     = (const float*)d_in[4];
  const float* W2     = (const float*)d_in[5];
  const float* U2     = (const float*)d_in[6];
  const float* b2     = (const float*)d_in[7];
  const float* Wd     = (const float*)d_in[8];
  const float* bd     = (const float*)d_in[9];
  float* out    = (float*)d_out;
  float* emb_zi = (float*)d_ws;         // 5000*256*4 = 5.12 MB scratch

  emb_gemm<<<dim3(VOCAB / 8), dim3(256), 0, stream>>>(emb, W1, b1, emb_zi);
  lstm_quad<<<dim3(NB), dim3(256), 0, stream>>>(
      tokens, emb_zi, U1, W2, U2, b2, Wd, bd, out);
}

// Round 22
// 234.079 us; speedup vs baseline: 1.0798x; 1.0798x over previous
//
#include <hip/hip_runtime.h>

typedef _Float16 hp2 __attribute__((ext_vector_type(2)));

#define NB    1024
#define TT    256
#define EE    100
#define VOCAB 5000
#define GG1   256   // 4*H1
#define GG2   128   // 4*H2

__device__ __forceinline__ float fast_sigmoid(float x) {
  return __builtin_amdgcn_rcpf(1.0f + __expf(-x));
}
__device__ __forceinline__ float fast_tanh(float x) {
  return 1.0f - 2.0f * __builtin_amdgcn_rcpf(1.0f + __expf(2.0f * x));
}

// Counted-wait barrier: drain LDS ops only; global (zx prefetch) stays in flight.
__device__ __forceinline__ void step_sync() {
  asm volatile("s_waitcnt lgkmcnt(0)" ::: "memory");
  __builtin_amdgcn_s_barrier();
  __builtin_amdgcn_sched_barrier(0);
}

// ---- K1: emb_zi[v][u*4+g] = b1[g*64+u] + sum_k emb[v][k]*W1[k][g*64+u] ----
__global__ __launch_bounds__(256) void emb_gemm(
    const float* __restrict__ emb, const float* __restrict__ W1,
    const float* __restrict__ b1, float* __restrict__ emb_zi)
{
  __shared__ float sE[8][EE];
  const int j  = threadIdx.x;           // column g*64+u
  const int v0 = blockIdx.x * 8;
  for (int idx = j; idx < 8 * EE; idx += 256) {
    int r = idx / EE, k = idx % EE;
    sE[r][k] = emb[(size_t)(v0 + r) * EE + k];
  }
  __syncthreads();
  float acc[8];
  const float bb = b1[j];
  #pragma unroll
  for (int r = 0; r < 8; ++r) acc[r] = bb;
  for (int k = 0; k < EE; ++k) {
    float w = W1[k * GG1 + j];
    #pragma unroll
    for (int r = 0; r < 8; ++r) acc[r] = fmaf(sE[r][k], w, acc[r]);
  }
  const int slot = (j & 63) * 4 + (j >> 6);   // u*4 + g
  #pragma unroll
  for (int r = 0; r < 8; ++r) emb_zi[(size_t)(v0 + r) * GG1 + slot] = acc[r];
}

// ---- K2: one block = one row, TWO waves (wave0 = L1, wave1 = L2) ----
// Round-16 structure verbatim; ONLY change: each gate's dot chain is split
// into two independent accumulators (8 chains/wave instead of 4) and the
// LDS b128 reads are hoisted ahead of the dot block — attacks the
// accumulator-chain latency that 2 waves/SIMD can't fully hide.
__global__ __launch_bounds__(128) __attribute__((amdgpu_waves_per_eu(2, 2)))
void lstm_dual(
    const int* __restrict__ tokens, const float* __restrict__ emb_zi,
    const float* __restrict__ U1,
    const float* __restrict__ W2, const float* __restrict__ U2, const float* __restrict__ b2,
    const float* __restrict__ Wd, const float* __restrict__ bd,
    float* __restrict__ out)
{
  __shared__ __align__(16) _Float16 sHB[2][96];  // 0..63 h1, 64..95 h2
  __shared__ int sTok[TT];

  const int tid = threadIdx.x;
  const int u   = tid & 63;
  const int wv  = tid >> 6;           // 0: L1 wave, 1: L2 wave
  const int row = blockIdx.x;

  // ---- stage tokens + zero h buffers ----
  ((int2*)sTok)[tid] = ((const int2*)(tokens + (size_t)row * TT))[tid];
  if (tid < 96) { sHB[0][tid] = (_Float16)0.0f; sHB[1][tid] = (_Float16)0.0f; }

  if (wv == 0) {
    // ================= L1 wave: lane u owns unit u =================
    hp2 wA[128];   // wA[4p+g] = {U1[2p][g*64+u], U1[2p+1][g*64+u]}, p=0..31
    #pragma unroll
    for (int p = 0; p < 32; ++p) {
      #pragma unroll
      for (int g = 0; g < 4; ++g) {
        hp2 w;
        w[0] = (_Float16)U1[(2 * p + 0) * GG1 + g * 64 + u];
        w[1] = (_Float16)U1[(2 * p + 1) * GG1 + g * 64 + u];
        wA[4 * p + g] = w;
      }
    }
    __syncthreads();                  // tokens + zeroed buffers visible

    float c1 = 0.f, h1r = 0.f;
    // ---- prologue: h1(0) from zx(0) (h1(-1)=0), write parity 0 ----
    {
      int tok0 = sTok[0];
      float4 zx0 = *(const float4*)&emb_zi[(size_t)tok0 * GG1 + 4 * u];
      if (tok0 != 0) {
        float iv = fast_sigmoid(zx0.x);
        float gv = fast_tanh(zx0.z);
        float ov = fast_sigmoid(zx0.w);
        c1 = iv * gv; h1r = ov * fast_tanh(c1);
      }
      sHB[0][u] = (_Float16)h1r;
    }
    int   tok_a = sTok[1];            // token for A-step t+1 = 1
    float4 zxa = *(const float4*)&emb_zi[(size_t)tok_a * GG1 + 4 * u];
    step_sync();                      // pairs with wave1's first sync

    for (int t = 0; t < TT; ++t) {
      if (t + 1 < TT) {               // ---- A(t+1): h1(t+1) from h1(t) ----
        // prefetch zx(t+2): rides across the barrier (counted wait)
        int tok_n = 0;
        float4 zxn = zxa;
        if (t + 2 < TT) {
          tok_n = sTok[t + 2];
          zxn = *(const float4*)&emb_zi[(size_t)tok_n * GG1 + 4 * u];
        }
        // hoist all 8 uniform b128 reads (pipelined LDS latency)
        const int4* rb = (const int4*)&sHB[t & 1][0];
        int4 hq0 = rb[0], hq1 = rb[1], hq2 = rb[2], hq3 = rb[3];
        int4 hq4 = rb[4], hq5 = rb[5], hq6 = rb[6], hq7 = rb[7];
        int4 hqa[8] = {hq0, hq1, hq2, hq3, hq4, hq5, hq6, hq7};
        // 8 independent chains: gate g, even/odd q
        float a0x = 0.f, a1x = 0.f, a2x = 0.f, a3x = 0.f;
        float a0y = 0.f, a1y = 0.f, a2y = 0.f, a3y = 0.f;
        #pragma unroll
        for (int q = 0; q < 8; q += 2) {
          int4 hqx = hqa[q], hqy = hqa[q + 1];
          #pragma unroll
          for (int pp = 0; pp < 4; ++pp) {
            const int px = 4 * q + pp, py = 4 * (q + 1) + pp;
            hp2 hvx = ((const hp2*)&hqx)[pp];
            hp2 hvy = ((const hp2*)&hqy)[pp];
            a0x = __builtin_amdgcn_fdot2(hvx, wA[4 * px + 0], a0x, false);
            a1x = __builtin_amdgcn_fdot2(hvx, wA[4 * px + 1], a1x, false);
            a2x = __builtin_amdgcn_fdot2(hvx, wA[4 * px + 2], a2x, false);
            a3x = __builtin_amdgcn_fdot2(hvx, wA[4 * px + 3], a3x, false);
            a0y = __builtin_amdgcn_fdot2(hvy, wA[4 * py + 0], a0y, false);
            a1y = __builtin_amdgcn_fdot2(hvy, wA[4 * py + 1], a1y, false);
            a2y = __builtin_amdgcn_fdot2(hvy, wA[4 * py + 2], a2y, false);
            a3y = __builtin_amdgcn_fdot2(hvy, wA[4 * py + 3], a3y, false);
          }
        }
        {
          const bool ma = (tok_a != 0);
          float iv = fast_sigmoid(a0x + a0y + zxa.x);
          float fv = fast_sigmoid(a1x + a1y + zxa.y);
          float gv = fast_tanh(a2x + a2y + zxa.z);
          float ov = fast_sigmoid(a3x + a3y + zxa.w);
          if (ma) { c1 = fv * c1 + iv * gv; h1r = ov * fast_tanh(c1); }
        }
        sHB[(t & 1) ^ 1][u] = (_Float16)h1r;
        tok_a = tok_n; zxa = zxn;
      }
      step_sync();
    }
  } else {
    // ================= L2 wave: unit u2 = u&31, k-half s = u>>5 =================
    const int u2 = u & 31;
    const int s  = u >> 5;
    hp2 wB[96];    // wB[4p+g] = {[W2;U2][k0][g*32+u2], [k0+1][...]}, k0 = 48s+2p
    #pragma unroll
    for (int p = 0; p < 24; ++p) {
      int k0 = 48 * s + 2 * p;        // even: never straddles the 64 boundary
      const float* r0 = (k0     < 64) ? &W2[(size_t)k0 * GG2]       : &U2[(size_t)(k0 - 64) * GG2];
      const float* r1 = (k0 + 1 < 64) ? &W2[(size_t)(k0 + 1) * GG2] : &U2[(size_t)(k0 + 1 - 64) * GG2];
      #pragma unroll
      for (int g = 0; g < 4; ++g) {
        hp2 w;
        w[0] = (_Float16)r0[g * 32 + u2];
        w[1] = (_Float16)r1[g * 32 + u2];
        wB[4 * p + g] = w;
      }
    }
    const float bi2 = b2[u2], bf2 = b2[32 + u2], bg2 = b2[64 + u2], bo2 = b2[96 + u2];
    __syncthreads();                  // tokens + zeroed buffers visible

    float c2 = 0.f, h2r = 0.f;
    step_sync();                      // pairs with wave0's prologue sync

    for (int t = 0; t < TT; ++t) {
      // ---- B(t): h2(t) from [h1(t) | h2(t-1)] at parity t&1 ----
      const int tok_b = sTok[t];
      const int4* hbp = (const int4*)(&sHB[t & 1][48 * s]);  // 2 addrs/wave
      int4 hq0 = hbp[0], hq1 = hbp[1], hq2 = hbp[2];
      int4 hq3 = hbp[3], hq4 = hbp[4], hq5 = hbp[5];
      int4 hqa[6] = {hq0, hq1, hq2, hq3, hq4, hq5};
      // 8 independent chains: gate g, even/odd q
      float b0x = 0.f, b1x = 0.f, b2x = 0.f, b3x = 0.f;
      float b0y = 0.f, b1y = 0.f, b2y = 0.f, b3y = 0.f;
      #pragma unroll
      for (int q = 0; q < 6; q += 2) {
        int4 hqx = hqa[q], hqy = hqa[q + 1];
        #pragma unroll
        for (int pp = 0; pp < 4; ++pp) {
          const int px = 4 * q + pp, py = 4 * (q + 1) + pp;
          hp2 hvx = ((const hp2*)&hqx)[pp];
          hp2 hvy = ((const hp2*)&hqy)[pp];
          b0x = __builtin_amdgcn_fdot2(hvx, wB[4 * px + 0], b0x, false);
          b1x = __builtin_amdgcn_fdot2(hvx, wB[4 * px + 1], b1x, false);
          b2x = __builtin_amdgcn_fdot2(hvx, wB[4 * px + 2], b2x, false);
          b3x = __builtin_amdgcn_fdot2(hvx, wB[4 * px + 3], b3x, false);
          b0y = __builtin_amdgcn_fdot2(hvy, wB[4 * py + 0], b0y, false);
          b1y = __builtin_amdgcn_fdot2(hvy, wB[4 * py + 1], b1y, false);
          b2y = __builtin_amdgcn_fdot2(hvy, wB[4 * py + 2], b2y, false);
          b3y = __builtin_amdgcn_fdot2(hvy, wB[4 * py + 3], b3y, false);
        }
      }
      float b0 = b0x + b0y, b1v = b1x + b1y, b2v = b2x + b2y, b3 = b3x + b3y;
      b0  += __shfl_xor(b0, 32);
      b1v += __shfl_xor(b1v, 32);
      b2v += __shfl_xor(b2v, 32);
      b3  += __shfl_xor(b3, 32);
      {
        const bool mb = (tok_b != 0);
        float i2 = fast_sigmoid(b0 + bi2);
        float f2 = fast_sigmoid(b1v + bf2);
        float g2 = fast_tanh(b2v + bg2);
        float o2 = fast_sigmoid(b3 + bo2);
        if (mb) { c2 = f2 * c2 + i2 * g2; h2r = o2 * fast_tanh(c2); }
      }
      if (s == 0) sHB[(t & 1) ^ 1][64 + u2] = (_Float16)h2r;
      step_sync();
    }
  }
  __syncthreads();

  // ---- epilogue: h2(TT-1) in parity ((TT-1)&1)^1 = 0 ----
  if (tid < 4) {
    float a = bd[tid];
    #pragma unroll
    for (int k = 0; k < 32; ++k)
      a = fmaf((float)sHB[0][64 + k], Wd[k * 4 + tid], a);
    out[(size_t)row * 4 + tid] = fast_sigmoid(a);
  }
}

extern "C" void kernel_launch(void* const* d_in, const int* in_sizes, int n_in,
                              void* d_out, int out_size, void* d_ws, size_t ws_size,
                              hipStream_t stream) {
  const int*   tokens = (const int*)d_in[0];
  const float* emb    = (const float*)d_in[1];
  const float* W1     = (const float*)d_in[2];
  const float* U1     = (const float*)d_in[3];
  const float* b1     = (const float*)d_in[4];
  const float* W2     = (const float*)d_in[5];
  const float* U2     = (const float*)d_in[6];
  const float* b2     = (const float*)d_in[7];
  const float* Wd     = (const float*)d_in[8];
  const float* bd     = (const float*)d_in[9];
  float* out    = (float*)d_out;
  float* emb_zi = (float*)d_ws;         // 5000*256*4 = 5.12 MB scratch

  emb_gemm<<<dim3(VOCAB / 8), dim3(256), 0, stream>>>(emb, W1, b1, emb_zi);
  lstm_dual<<<dim3(NB), dim3(128), 0, stream>>>(
      tokens, emb_zi, U1, W2, U2, b2, Wd, bd, out);
}